// Round 1
// baseline (5300.068 us; speedup 1.0000x reference)
//
#include <hip/hip_runtime.h>

#define ALPHA 0.1f
#define KITER 16

struct __align__(8) EdgeRec { int src; float w; };

// ---------------------------------------------------------------- init
__global__ void k_init(int* cnt, int* cursor, int* flag, int n) {
    int i = blockIdx.x * blockDim.x + threadIdx.x;
    if (i < n) { cnt[i] = 0; cursor[i] = 0; }
    if (blockIdx.x == 0 && threadIdx.x == 0) *flag = 1;
}

// Detect int64 vs int32 edge_index: if stored int64 (values < 2^31), every
// odd 32-bit word of the first rows is 0. Any nonzero => int32.
__global__ void k_detect(const int* ew, int e, int* flag) {
    int t = blockIdx.x * blockDim.x + threadIdx.x;
    if (t < 512 && t < e) {
        if (ew[2 * t + 1] != 0) atomicAnd(flag, 0);
    }
}

// ---------------------------------------------------------------- degree histogram (over col = target)
__global__ void k_hist(const void* eptr, int e, const int* flag, int* cnt) {
    int i = blockIdx.x * blockDim.x + threadIdx.x;
    if (i >= e) return;
    int c;
    if (*flag) c = (int)((const long long*)eptr)[(long long)e + i];
    else       c = ((const int*)eptr)[(long long)e + i];
    atomicAdd(&cnt[c], 1);
}

__global__ void k_dinv(const int* cnt, float* dinv, float* dinv2, int n) {
    int i = blockIdx.x * blockDim.x + threadIdx.x;
    if (i >= n) return;
    float d = (float)(cnt[i] + 1);   // +1 self-loop
    float r = 1.0f / sqrtf(d);
    dinv[i] = r;
    dinv2[i] = r * r;
}

// ---------------------------------------------------------------- exclusive scan (row_ptr)
#define SCAN_B 1024
__global__ void k_scan1(const int* cnt, int n, int* rowptr, int* bsum) {
    __shared__ int s[SCAN_B];
    int tid = threadIdx.x;
    int i = blockIdx.x * SCAN_B + tid;
    int v = (i < n) ? cnt[i] : 0;
    s[tid] = v;
    __syncthreads();
    for (int off = 1; off < SCAN_B; off <<= 1) {
        int t = (tid >= off) ? s[tid - off] : 0;
        __syncthreads();
        s[tid] += t;
        __syncthreads();
    }
    if (i < n) rowptr[i] = s[tid] - v;            // exclusive
    if (tid == SCAN_B - 1) bsum[blockIdx.x] = s[tid];
}

__global__ void k_scan2(int* bsum, int nb, int* rowptr, int n) {
    if (blockIdx.x == 0 && threadIdx.x == 0) {
        int run = 0;
        for (int b = 0; b < nb; ++b) { int t = bsum[b]; bsum[b] = run; run += t; }
        rowptr[n] = run;
    }
}

__global__ void k_scan3(int* rowptr, const int* bsum, int n) {
    int i = blockIdx.x * blockDim.x + threadIdx.x;
    if (i < n) rowptr[i] += bsum[i / SCAN_B];
}

// ---------------------------------------------------------------- CSR scatter
__global__ void k_scatter(const void* eptr, int e, const int* flag,
                          const int* rowptr, int* cursor, const float* dinv,
                          EdgeRec* rec) {
    int i = blockIdx.x * blockDim.x + threadIdx.x;
    if (i >= e) return;
    int s, c;
    if (*flag) {
        const long long* p = (const long long*)eptr;
        s = (int)p[i];
        c = (int)p[(long long)e + i];
    } else {
        const int* p = (const int*)eptr;
        s = p[i];
        c = p[(long long)e + i];
    }
    int pos = rowptr[c] + atomicAdd(&cursor[c], 1);
    EdgeRec r; r.src = s; r.w = dinv[s] * dinv[c];
    rec[pos] = r;
}

// ---------------------------------------------------------------- fused MLP: x0 = relu(x@W1+b1)@W2+b2
// 64 rows per block, 256 threads. Phase1: 64x128 h1 tile in regs.
// Phase2: h1 tile via LDS, @ W2(128x64) -> 64x64 out tile.
__global__ __launch_bounds__(256) void k_mlp(const float* __restrict__ x,
        const float* __restrict__ W1, const float* __restrict__ b1,
        const float* __restrict__ W2, const float* __restrict__ b2,
        float* __restrict__ x0, int n) {
    __shared__ union {
        struct { float As[32][68]; float Bs[32][128]; } p1;
        struct { float Hs[64][132]; float Ws[128][64]; float b2s[64]; } p2;
    } sm;

    const int tid = threadIdx.x;
    const int tc = tid & 31;        // 32 col-groups
    const int tr = tid >> 5;        // 8 row-groups (8 rows each)
    const int bm0 = blockIdx.x * 64;

    float acc[8][4];
#pragma unroll
    for (int i = 0; i < 8; ++i)
#pragma unroll
        for (int j = 0; j < 4; ++j) acc[i][j] = 0.0f;

    const int ar = tid >> 2;            // 0..63 (row within tile)
    const int ak = (tid & 3) * 8;       // k offset within tile
    const long long arow = (long long)bm0 + ar;
    const bool avalid = arow < n;
    const float* aptr = x + arow * 512 + ak;
    const int bk = tid >> 3;            // 0..31
    const int bj = (tid & 7) * 16;

    for (int kt = 0; kt < 16; ++kt) {
        const int k0 = kt * 32;
        float4 a0 = {0, 0, 0, 0}, a1 = {0, 0, 0, 0};
        if (avalid) {
            a0 = *(const float4*)(aptr + k0);
            a1 = *(const float4*)(aptr + k0 + 4);
        }
        sm.p1.As[ak + 0][ar] = a0.x; sm.p1.As[ak + 1][ar] = a0.y;
        sm.p1.As[ak + 2][ar] = a0.z; sm.p1.As[ak + 3][ar] = a0.w;
        sm.p1.As[ak + 4][ar] = a1.x; sm.p1.As[ak + 5][ar] = a1.y;
        sm.p1.As[ak + 6][ar] = a1.z; sm.p1.As[ak + 7][ar] = a1.w;

        const float* wp = W1 + (long long)(k0 + bk) * 128 + bj;
        float4 w0 = *(const float4*)(wp + 0);
        float4 w1 = *(const float4*)(wp + 4);
        float4 w2 = *(const float4*)(wp + 8);
        float4 w3 = *(const float4*)(wp + 12);
        *(float4*)&sm.p1.Bs[bk][bj + 0]  = w0;
        *(float4*)&sm.p1.Bs[bk][bj + 4]  = w1;
        *(float4*)&sm.p1.Bs[bk][bj + 8]  = w2;
        *(float4*)&sm.p1.Bs[bk][bj + 12] = w3;
        __syncthreads();

#pragma unroll
        for (int kk = 0; kk < 32; ++kk) {
            float4 av0 = *(const float4*)&sm.p1.As[kk][tr * 8];
            float4 av1 = *(const float4*)&sm.p1.As[kk][tr * 8 + 4];
            float4 bv  = *(const float4*)&sm.p1.Bs[kk][tc * 4];
            float a_[8] = {av0.x, av0.y, av0.z, av0.w, av1.x, av1.y, av1.z, av1.w};
            float b_[4] = {bv.x, bv.y, bv.z, bv.w};
#pragma unroll
            for (int i = 0; i < 8; ++i)
#pragma unroll
                for (int j = 0; j < 4; ++j)
                    acc[i][j] = fmaf(a_[i], b_[j], acc[i][j]);
        }
        __syncthreads();
    }

    // relu + b1, write h1 tile to LDS
    float4 bb = *(const float4*)(b1 + tc * 4);
#pragma unroll
    for (int i = 0; i < 8; ++i) {
        float4 h;
        h.x = fmaxf(acc[i][0] + bb.x, 0.0f);
        h.y = fmaxf(acc[i][1] + bb.y, 0.0f);
        h.z = fmaxf(acc[i][2] + bb.z, 0.0f);
        h.w = fmaxf(acc[i][3] + bb.w, 0.0f);
        *(float4*)&sm.p2.Hs[tr * 8 + i][tc * 4] = h;
    }
    // load W2 into LDS: 8192 floats, 32 per thread
    {
        const int kw = tid >> 1;
        const int j0 = (tid & 1) * 32;
        const float* wp2 = W2 + kw * 64 + j0;
#pragma unroll
        for (int q = 0; q < 8; ++q)
            *(float4*)&sm.p2.Ws[kw][j0 + q * 4] = *(const float4*)(wp2 + q * 4);
    }
    if (tid < 64) sm.p2.b2s[tid] = b2[tid];
    __syncthreads();

    float acc2[8][2];
#pragma unroll
    for (int i = 0; i < 8; ++i) { acc2[i][0] = 0.0f; acc2[i][1] = 0.0f; }

#pragma unroll 8
    for (int k4 = 0; k4 < 32; ++k4) {
        float4 a4[8];
#pragma unroll
        for (int i = 0; i < 8; ++i)
            a4[i] = *(const float4*)&sm.p2.Hs[tr * 8 + i][k4 * 4];
        float2 w0 = *(const float2*)&sm.p2.Ws[k4 * 4 + 0][tc * 2];
        float2 w1 = *(const float2*)&sm.p2.Ws[k4 * 4 + 1][tc * 2];
        float2 w2 = *(const float2*)&sm.p2.Ws[k4 * 4 + 2][tc * 2];
        float2 w3 = *(const float2*)&sm.p2.Ws[k4 * 4 + 3][tc * 2];
#pragma unroll
        for (int i = 0; i < 8; ++i) {
            acc2[i][0] = fmaf(a4[i].x, w0.x, acc2[i][0]);
            acc2[i][1] = fmaf(a4[i].x, w0.y, acc2[i][1]);
            acc2[i][0] = fmaf(a4[i].y, w1.x, acc2[i][0]);
            acc2[i][1] = fmaf(a4[i].y, w1.y, acc2[i][1]);
            acc2[i][0] = fmaf(a4[i].z, w2.x, acc2[i][0]);
            acc2[i][1] = fmaf(a4[i].z, w2.y, acc2[i][1]);
            acc2[i][0] = fmaf(a4[i].w, w3.x, acc2[i][0]);
            acc2[i][1] = fmaf(a4[i].w, w3.y, acc2[i][1]);
        }
    }

    const float bo0 = sm.p2.b2s[tc * 2];
    const float bo1 = sm.p2.b2s[tc * 2 + 1];
#pragma unroll
    for (int i = 0; i < 8; ++i) {
        long long g = (long long)bm0 + tr * 8 + i;
        if (g < n) {
            float2 o;
            o.x = acc2[i][0] + bo0;
            o.y = acc2[i][1] + bo1;
            *(float2*)&x0[g * 64 + tc * 2] = o;
        }
    }
}

// ---------------------------------------------------------------- propagation: one wave per node, lane = channel
__global__ __launch_bounds__(256) void k_prop(const float* __restrict__ zin,
        const float* __restrict__ x0, const int* __restrict__ rowptr,
        const EdgeRec* __restrict__ rec, const float* __restrict__ dinv2,
        float* __restrict__ zout, int n) {
    int node = blockIdx.x * 4 + (threadIdx.x >> 6);
    if (node >= n) return;
    int lane = threadIdx.x & 63;
    long long base = (long long)node * 64 + lane;
    float acc = dinv2[node] * zin[base];           // self loop
    int e0 = rowptr[node], e1 = rowptr[node + 1];
    for (int e = e0; e < e1; ++e) {
        EdgeRec r = rec[e];
        acc = fmaf(r.w, zin[(long long)r.src * 64 + lane], acc);
    }
    zout[base] = (1.0f - ALPHA) * acc + ALPHA * x0[base];
}

// ---------------------------------------------------------------- log_softmax in place (row = wave)
__global__ __launch_bounds__(256) void k_lsm(float* z, int n) {
    int node = blockIdx.x * 4 + (threadIdx.x >> 6);
    if (node >= n) return;
    int lane = threadIdx.x & 63;
    long long base = (long long)node * 64 + lane;
    float v = z[base];
    float m = v;
#pragma unroll
    for (int o = 32; o >= 1; o >>= 1) m = fmaxf(m, __shfl_xor(m, o, 64));
    float e = expf(v - m);
    float s = e;
#pragma unroll
    for (int o = 32; o >= 1; o >>= 1) s += __shfl_xor(s, o, 64);
    z[base] = v - m - logf(s);
}

// ---------------------------------------------------------------- launch
extern "C" void kernel_launch(void* const* d_in, const int* in_sizes, int n_in,
                              void* d_out, int out_size, void* d_ws, size_t ws_size,
                              hipStream_t stream) {
    const float* x  = (const float*)d_in[0];
    const void*  ei = d_in[1];
    const float* W1 = (const float*)d_in[2];
    const float* b1 = (const float*)d_in[3];
    const float* W2 = (const float*)d_in[4];
    const float* b2 = (const float*)d_in[5];
    float* out = (float*)d_out;

    const int n = in_sizes[0] / 512;
    const int E = in_sizes[1] / 2;

    char* p = (char*)d_ws;
    auto alloc = [&](size_t bytes) {
        void* r = (void*)p;
        p += (bytes + 255) & ~(size_t)255;
        return r;
    };
    int*     cnt    = (int*)alloc((size_t)n * 4);
    int*     cursor = (int*)alloc((size_t)n * 4);
    int*     rowptr = (int*)alloc((size_t)(n + 1) * 4);
    int*     bsum   = (int*)alloc(256 * 4);
    int*     flag   = (int*)alloc(4);
    float*   dinv   = (float*)alloc((size_t)n * 4);
    float*   dinv2  = (float*)alloc((size_t)n * 4);
    EdgeRec* rec    = (EdgeRec*)alloc((size_t)E * 8);
    float*   x0     = (float*)alloc((size_t)n * 64 * 4);
    float*   zA     = (float*)alloc((size_t)n * 64 * 4);

    const int nb = (n + SCAN_B - 1) / SCAN_B;

    k_init<<<(n + 255) / 256, 256, 0, stream>>>(cnt, cursor, flag, n);
    k_detect<<<2, 256, 0, stream>>>((const int*)ei, E, flag);
    k_hist<<<(E + 255) / 256, 256, 0, stream>>>(ei, E, flag, cnt);
    k_dinv<<<(n + 255) / 256, 256, 0, stream>>>(cnt, dinv, dinv2, n);
    k_scan1<<<nb, SCAN_B, 0, stream>>>(cnt, n, rowptr, bsum);
    k_scan2<<<1, 64, 0, stream>>>(bsum, nb, rowptr, n);
    k_scan3<<<(n + 255) / 256, 256, 0, stream>>>(rowptr, bsum, n);
    k_scatter<<<(E + 255) / 256, 256, 0, stream>>>(ei, E, flag, rowptr, cursor, dinv, rec);
    k_mlp<<<(n + 63) / 64, 256, 0, stream>>>(x, W1, b1, W2, b2, x0, n);

    const float* zi = x0;
    float* zo = zA;
    for (int it = 0; it < KITER; ++it) {
        k_prop<<<(n + 3) / 4, 256, 0, stream>>>(zi, x0, rowptr, rec, dinv2, zo, n);
        zi = zo;
        zo = (zo == zA) ? out : zA;
    }
    // after 16 iterations z lives in `out`
    k_lsm<<<(n + 3) / 4, 256, 0, stream>>>(out, n);
}

// Round 2
// 2214.855 us; speedup vs baseline: 2.3930x; 2.3930x over previous
//
#include <hip/hip_runtime.h>

#define ALPHA 0.1f
#define KITER 16

struct __align__(8) EdgeRec { int src; float w; };

typedef __attribute__((ext_vector_type(8))) short short8;
typedef __attribute__((ext_vector_type(4))) float f32x4;

__device__ __forceinline__ unsigned short f2bf(float f) {
    unsigned int u = __float_as_uint(f);
    u = (u + 0x7fffu + ((u >> 16) & 1u)) >> 16;
    return (unsigned short)u;
}

// ---------------------------------------------------------------- init
__global__ void k_init(int* cnt, int* cursor, int* flag, int n) {
    int i = blockIdx.x * blockDim.x + threadIdx.x;
    if (i < n) { cnt[i] = 0; cursor[i] = 0; }
    if (blockIdx.x == 0 && threadIdx.x == 0) *flag = 1;
}

// Detect int64 vs int32 edge_index
__global__ void k_detect(const int* ew, int e, int* flag) {
    int t = blockIdx.x * blockDim.x + threadIdx.x;
    if (t < 512 && t < e) {
        if (ew[2 * t + 1] != 0) atomicAnd(flag, 0);
    }
}

// ---------------------------------------------------------------- degree histogram (over col = target)
__global__ void k_hist(const void* eptr, int e, const int* flag, int* cnt) {
    int i = blockIdx.x * blockDim.x + threadIdx.x;
    if (i >= e) return;
    int c;
    if (*flag) c = (int)((const long long*)eptr)[(long long)e + i];
    else       c = ((const int*)eptr)[(long long)e + i];
    atomicAdd(&cnt[c], 1);
}

__global__ void k_dinv(const int* cnt, float* dinv, float* dinv2, int n) {
    int i = blockIdx.x * blockDim.x + threadIdx.x;
    if (i >= n) return;
    float d = (float)(cnt[i] + 1);   // +1 self-loop
    float r = 1.0f / sqrtf(d);
    dinv[i] = r;
    dinv2[i] = r * r;
}

// ---------------------------------------------------------------- exclusive scan (row_ptr)
#define SCAN_B 1024
__global__ void k_scan1(const int* cnt, int n, int* rowptr, int* bsum) {
    __shared__ int s[SCAN_B];
    int tid = threadIdx.x;
    int i = blockIdx.x * SCAN_B + tid;
    int v = (i < n) ? cnt[i] : 0;
    s[tid] = v;
    __syncthreads();
    for (int off = 1; off < SCAN_B; off <<= 1) {
        int t = (tid >= off) ? s[tid - off] : 0;
        __syncthreads();
        s[tid] += t;
        __syncthreads();
    }
    if (i < n) rowptr[i] = s[tid] - v;            // exclusive
    if (tid == SCAN_B - 1) bsum[blockIdx.x] = s[tid];
}

__global__ void k_scan2(int* bsum, int nb, int* rowptr, int n) {
    if (blockIdx.x == 0 && threadIdx.x == 0) {
        int run = 0;
        for (int b = 0; b < nb; ++b) { int t = bsum[b]; bsum[b] = run; run += t; }
        rowptr[n] = run;
    }
}

__global__ void k_scan3(int* rowptr, const int* bsum, int n) {
    int i = blockIdx.x * blockDim.x + threadIdx.x;
    if (i < n) rowptr[i] += bsum[i / SCAN_B];
}

// ---------------------------------------------------------------- CSR scatter
__global__ void k_scatter(const void* eptr, int e, const int* flag,
                          const int* rowptr, int* cursor, const float* dinv,
                          EdgeRec* rec) {
    int i = blockIdx.x * blockDim.x + threadIdx.x;
    if (i >= e) return;
    int s, c;
    if (*flag) {
        const long long* p = (const long long*)eptr;
        s = (int)p[i];
        c = (int)p[(long long)e + i];
    } else {
        const int* p = (const int*)eptr;
        s = p[i];
        c = p[(long long)e + i];
    }
    int pos = rowptr[c] + atomicAdd(&cursor[c], 1);
    EdgeRec r; r.src = s; r.w = dinv[s] * dinv[c];
    rec[pos] = r;
}

// ---------------------------------------------------------------- W1/W2 -> bf16 MFMA-fragment layout
// W1f[kt(16)][nf(8)][lane(64)][elem(8)] : B-frag of mfma_f32_16x16x32_bf16
//   k = kt*32 + 8*(lane>>4) + elem ; nn = nf*16 + (lane&15)
// W2f[kt2(4)][nf(4)][lane(64)][elem(8)]
__global__ void k_wprep(const float* __restrict__ W1, const float* __restrict__ W2,
                        unsigned short* __restrict__ W1f, unsigned short* __restrict__ W2f) {
    int t = blockIdx.x * 256 + threadIdx.x;
    if (t < 65536) {
        int e = t & 7, lane = (t >> 3) & 63, nf = (t >> 9) & 7, kt = t >> 12;
        int k = kt * 32 + 8 * (lane >> 4) + e;
        int nn = nf * 16 + (lane & 15);
        W1f[t] = f2bf(W1[k * 128 + nn]);
    } else if (t < 65536 + 8192) {
        int t2 = t - 65536;
        int e = t2 & 7, lane = (t2 >> 3) & 63, nf = (t2 >> 9) & 3, kt2 = t2 >> 11;
        int k = kt2 * 32 + 8 * (lane >> 4) + e;
        int nn = nf * 16 + (lane & 15);
        W2f[t2] = f2bf(W2[k * 64 + nn]);
    }
}

// ---------------------------------------------------------------- MFMA MLP: x0 = relu(x@W1+b1)@W2+b2
// 64 rows / block, 256 threads = 4 waves. Phase1: N=128 split 32 cols/wave.
// A-fragment layout for 16x16x32: row = lane&15, k = 8*(lane>>4)+elem.
// C/D layout: col = lane&15, row = 4*(lane>>4)+reg.
__global__ __launch_bounds__(256) void k_mlp(const float* __restrict__ x,
        const unsigned short* __restrict__ W1f, const float* __restrict__ b1,
        const unsigned short* __restrict__ W2f, const float* __restrict__ b2,
        float* __restrict__ x0, int n) {
    __shared__ unsigned short Xs[4][64][8];       // A-frags for current K-step (4 KB)
    __shared__ unsigned short Hs[4][4][64][8];    // h in A-frag layout, all K (16 KB)

    const int tid  = threadIdx.x;
    const int lane = tid & 63;
    const int wv   = tid >> 6;          // wave id: owns phase1 cols wv*32..wv*32+31
    const int bm0  = blockIdx.x * 64;

    // staging role: thread t -> row = t>>2, kgroup = t&3 (8 consecutive k)
    const int sr = tid >> 2;
    const int sk = tid & 3;
    const long long srow = (long long)bm0 + sr;
    const bool svalid = srow < n;
    const float* xp = x + srow * 512 + sk * 8;

    f32x4 acc[4][2];
#pragma unroll
    for (int mf = 0; mf < 4; ++mf)
#pragma unroll
        for (int nf = 0; nf < 2; ++nf) acc[mf][nf] = (f32x4){0.f, 0.f, 0.f, 0.f};

    for (int kt = 0; kt < 16; ++kt) {
        // ---- stage X tile (64x32 fp32 -> bf16, directly in A-frag layout)
        float4 f0 = {0, 0, 0, 0}, f1 = {0, 0, 0, 0};
        if (svalid) {
            f0 = *(const float4*)(xp + kt * 32);
            f1 = *(const float4*)(xp + kt * 32 + 4);
        }
        uint4 pk;
        pk.x = (unsigned int)f2bf(f0.x) | ((unsigned int)f2bf(f0.y) << 16);
        pk.y = (unsigned int)f2bf(f0.z) | ((unsigned int)f2bf(f0.w) << 16);
        pk.z = (unsigned int)f2bf(f1.x) | ((unsigned int)f2bf(f1.y) << 16);
        pk.w = (unsigned int)f2bf(f1.z) | ((unsigned int)f2bf(f1.w) << 16);
        *(uint4*)&Xs[sr >> 4][(sr & 15) + 16 * sk][0] = pk;
        __syncthreads();

        // ---- 8 MFMAs: 4 m-frags x 2 n-frags
        short8 bf[2];
#pragma unroll
        for (int nf = 0; nf < 2; ++nf)
            bf[nf] = *(const short8*)(W1f + (((size_t)kt * 8 + wv * 2 + nf) * 64 + lane) * 8);
#pragma unroll
        for (int mf = 0; mf < 4; ++mf) {
            short8 af = *(const short8*)&Xs[mf][lane][0];
#pragma unroll
            for (int nf = 0; nf < 2; ++nf)
                acc[mf][nf] = __builtin_amdgcn_mfma_f32_16x16x32_bf16(af, bf[nf], acc[mf][nf], 0, 0, 0);
        }
        __syncthreads();
    }

    // ---- bias + relu + bf16, transpose into Hs (A-frag layout over K=128)
    const int c0 = wv * 32 + (lane & 15);
    const float b1v0 = b1[c0];
    const float b1v1 = b1[c0 + 16];
#pragma unroll
    for (int mf = 0; mf < 4; ++mf) {
#pragma unroll
        for (int nf = 0; nf < 2; ++nf) {
            float bb = nf ? b1v1 : b1v0;
            int k = wv * 32 + nf * 16 + (lane & 15);    // h column = phase2 K index
#pragma unroll
            for (int r = 0; r < 4; ++r) {
                int row = mf * 16 + 4 * (lane >> 4) + r;
                float h = fmaxf(acc[mf][nf][r] + bb, 0.0f);
                Hs[wv][row >> 4][(row & 15) + 16 * ((k >> 3) & 3)][k & 7] = f2bf(h);
            }
        }
    }
    __syncthreads();

    // ---- phase 2: out[64][64] = Hs @ W2f ; wave owns n-frag = wv
    f32x4 acc2[4];
#pragma unroll
    for (int mf = 0; mf < 4; ++mf) acc2[mf] = (f32x4){0.f, 0.f, 0.f, 0.f};
#pragma unroll
    for (int kt2 = 0; kt2 < 4; ++kt2) {
        short8 bf2 = *(const short8*)(W2f + (((size_t)kt2 * 4 + wv) * 64 + lane) * 8);
#pragma unroll
        for (int mf = 0; mf < 4; ++mf) {
            short8 af2 = *(const short8*)&Hs[kt2][mf][lane][0];
            acc2[mf] = __builtin_amdgcn_mfma_f32_16x16x32_bf16(af2, bf2, acc2[mf], 0, 0, 0);
        }
    }

    const int oc = wv * 16 + (lane & 15);
    const float bo = b2[oc];
#pragma unroll
    for (int mf = 0; mf < 4; ++mf) {
#pragma unroll
        for (int r = 0; r < 4; ++r) {
            long long row = (long long)bm0 + mf * 16 + 4 * (lane >> 4) + r;
            if (row < n) x0[row * 64 + oc] = acc2[mf][r] + bo;
        }
    }
}

// ---------------------------------------------------------------- propagation: one wave per node, lane = channel
// node made wave-uniform -> rowptr/rec loads become scalar; 4 independent
// accumulator chains keep 4 gathers in flight.
__global__ __launch_bounds__(256) void k_prop(const float* __restrict__ zin,
        const float* __restrict__ x0, const int* __restrict__ rowptr,
        const EdgeRec* __restrict__ rec, const float* __restrict__ dinv2,
        float* __restrict__ zout, int n) {
    int node = __builtin_amdgcn_readfirstlane(blockIdx.x * 4 + (threadIdx.x >> 6));
    if (node >= n) return;
    const int lane = threadIdx.x & 63;
    const long long base = ((long long)node << 6) + lane;
    const int e0 = rowptr[node], e1 = rowptr[node + 1];
    const long long* __restrict__ recq = (const long long*)rec;

    float a0 = dinv2[node] * zin[base];            // self loop
    float a1 = 0.f, a2 = 0.f, a3 = 0.f;
    int e = e0;
    for (; e + 4 <= e1; e += 4) {
        long long q0 = recq[e],     q1 = recq[e + 1];
        long long q2 = recq[e + 2], q3 = recq[e + 3];
        float z0 = zin[((long long)(int)q0 << 6) + lane];
        float z1 = zin[((long long)(int)q1 << 6) + lane];
        float z2 = zin[((long long)(int)q2 << 6) + lane];
        float z3 = zin[((long long)(int)q3 << 6) + lane];
        a0 = fmaf(__int_as_float((int)(q0 >> 32)), z0, a0);
        a1 = fmaf(__int_as_float((int)(q1 >> 32)), z1, a1);
        a2 = fmaf(__int_as_float((int)(q2 >> 32)), z2, a2);
        a3 = fmaf(__int_as_float((int)(q3 >> 32)), z3, a3);
    }
    for (; e < e1; ++e) {
        long long q = recq[e];
        float zv = zin[((long long)(int)q << 6) + lane];
        a0 = fmaf(__int_as_float((int)(q >> 32)), zv, a0);
    }
    float acc = (a0 + a1) + (a2 + a3);
    zout[base] = (1.0f - ALPHA) * acc + ALPHA * x0[base];
}

// ---------------------------------------------------------------- log_softmax in place (row = wave)
__global__ __launch_bounds__(256) void k_lsm(float* z, int n) {
    int node = blockIdx.x * 4 + (threadIdx.x >> 6);
    if (node >= n) return;
    int lane = threadIdx.x & 63;
    long long base = ((long long)node << 6) + lane;
    float v = z[base];
    float m = v;
#pragma unroll
    for (int o = 32; o >= 1; o >>= 1) m = fmaxf(m, __shfl_xor(m, o, 64));
    float e = expf(v - m);
    float s = e;
#pragma unroll
    for (int o = 32; o >= 1; o >>= 1) s += __shfl_xor(s, o, 64);
    z[base] = v - m - logf(s);
}

// ---------------------------------------------------------------- launch
extern "C" void kernel_launch(void* const* d_in, const int* in_sizes, int n_in,
                              void* d_out, int out_size, void* d_ws, size_t ws_size,
                              hipStream_t stream) {
    const float* x  = (const float*)d_in[0];
    const void*  ei = d_in[1];
    const float* W1 = (const float*)d_in[2];
    const float* b1 = (const float*)d_in[3];
    const float* W2 = (const float*)d_in[4];
    const float* b2 = (const float*)d_in[5];
    float* out = (float*)d_out;

    const int n = in_sizes[0] / 512;
    const int E = in_sizes[1] / 2;

    char* p = (char*)d_ws;
    auto alloc = [&](size_t bytes) {
        void* r = (void*)p;
        p += (bytes + 255) & ~(size_t)255;
        return r;
    };
    int*     cnt    = (int*)alloc((size_t)n * 4);
    int*     cursor = (int*)alloc((size_t)n * 4);
    int*     rowptr = (int*)alloc((size_t)(n + 1) * 4);
    int*     bsum   = (int*)alloc(256 * 4);
    int*     flag   = (int*)alloc(4);
    float*   dinv   = (float*)alloc((size_t)n * 4);
    float*   dinv2  = (float*)alloc((size_t)n * 4);
    EdgeRec* rec    = (EdgeRec*)alloc((size_t)E * 8);
    float*   x0     = (float*)alloc((size_t)n * 64 * 4);
    float*   zA     = (float*)alloc((size_t)n * 64 * 4);
    unsigned short* W1f = (unsigned short*)alloc(65536 * 2);
    unsigned short* W2f = (unsigned short*)alloc(8192 * 2);

    const int nb = (n + SCAN_B - 1) / SCAN_B;

    k_init<<<(n + 255) / 256, 256, 0, stream>>>(cnt, cursor, flag, n);
    k_detect<<<2, 256, 0, stream>>>((const int*)ei, E, flag);
    k_wprep<<<(65536 + 8192 + 255) / 256, 256, 0, stream>>>(W1, W2, W1f, W2f);
    k_hist<<<(E + 255) / 256, 256, 0, stream>>>(ei, E, flag, cnt);
    k_dinv<<<(n + 255) / 256, 256, 0, stream>>>(cnt, dinv, dinv2, n);
    k_scan1<<<nb, SCAN_B, 0, stream>>>(cnt, n, rowptr, bsum);
    k_scan2<<<1, 64, 0, stream>>>(bsum, nb, rowptr, n);
    k_scan3<<<(n + 255) / 256, 256, 0, stream>>>(rowptr, bsum, n);
    k_scatter<<<(E + 255) / 256, 256, 0, stream>>>(ei, E, flag, rowptr, cursor, dinv, rec);
    k_mlp<<<(n + 63) / 64, 256, 0, stream>>>(x, W1f, b1, W2f, b2, x0, n);

    const float* zi = x0;
    float* zo = zA;
    for (int it = 0; it < KITER; ++it) {
        k_prop<<<(n + 3) / 4, 256, 0, stream>>>(zi, x0, rowptr, rec, dinv2, zo, n);
        zi = zo;
        zo = (zo == zA) ? out : zA;
    }
    // after 16 iterations z lives in `out`
    k_lsm<<<(n + 3) / 4, 256, 0, stream>>>(out, n);
}

// Round 3
// 1485.336 us; speedup vs baseline: 3.5683x; 1.4911x over previous
//
#include <hip/hip_runtime.h>

#define KITER 16

typedef __attribute__((ext_vector_type(8))) short short8;
typedef __attribute__((ext_vector_type(4))) float f32x4;

__device__ __forceinline__ unsigned short f2bf(float f) {
    unsigned int u = __float_as_uint(f);
    u = (u + 0x7fffu + ((u >> 16) & 1u)) >> 16;
    return (unsigned short)u;
}
__device__ __forceinline__ float bf2f(unsigned short h) {
    return __uint_as_float(((unsigned int)h) << 16);
}

// ---------------------------------------------------------------- init
__global__ void k_init(int* cnt, int* cursor, int* flag, int n) {
    int i = blockIdx.x * blockDim.x + threadIdx.x;
    if (i < n) { cnt[i] = 0; cursor[i] = 0; }
    if (blockIdx.x == 0 && threadIdx.x == 0) *flag = 1;
}

// Detect int64 vs int32 edge_index
__global__ void k_detect(const int* ew, int e, int* flag) {
    int t = blockIdx.x * blockDim.x + threadIdx.x;
    if (t < 512 && t < e) {
        if (ew[2 * t + 1] != 0) atomicAnd(flag, 0);
    }
}

// ---------------------------------------------------------------- degree histogram (over col = target)
__global__ void k_hist(const void* eptr, int e, const int* flag, int* cnt) {
    int i = blockIdx.x * blockDim.x + threadIdx.x;
    if (i >= e) return;
    int c;
    if (*flag) c = (int)((const long long*)eptr)[(long long)e + i];
    else       c = ((const int*)eptr)[(long long)e + i];
    atomicAdd(&cnt[c], 1);
}

__global__ void k_dinv(const int* cnt, float* dinv, int n) {
    int i = blockIdx.x * blockDim.x + threadIdx.x;
    if (i >= n) return;
    float d = (float)(cnt[i] + 1);   // +1 self-loop
    dinv[i] = 1.0f / sqrtf(d);
}

// ---------------------------------------------------------------- exclusive scan (row_ptr)
#define SCAN_B 1024
__global__ void k_scan1(const int* cnt, int n, int* rowptr, int* bsum) {
    __shared__ int s[SCAN_B];
    int tid = threadIdx.x;
    int i = blockIdx.x * SCAN_B + tid;
    int v = (i < n) ? cnt[i] : 0;
    s[tid] = v;
    __syncthreads();
    for (int off = 1; off < SCAN_B; off <<= 1) {
        int t = (tid >= off) ? s[tid - off] : 0;
        __syncthreads();
        s[tid] += t;
        __syncthreads();
    }
    if (i < n) rowptr[i] = s[tid] - v;            // exclusive
    if (tid == SCAN_B - 1) bsum[blockIdx.x] = s[tid];
}

__global__ void k_scan2(int* bsum, int nb, int* rowptr, int n) {
    if (blockIdx.x == 0 && threadIdx.x == 0) {
        int run = 0;
        for (int b = 0; b < nb; ++b) { int t = bsum[b]; bsum[b] = run; run += t; }
        rowptr[n] = run;
    }
}

__global__ void k_scan3(int* rowptr, const int* bsum, int n) {
    int i = blockIdx.x * blockDim.x + threadIdx.x;
    if (i < n) rowptr[i] += bsum[i / SCAN_B];
}

// ---------------------------------------------------------------- CSR scatter, target-chunked
// 8 passes; pass ch only writes targets in [lo,hi) -> live write region
// ~1.6 MB, L2-resident, partial cachelines merge before writeback.
__global__ __launch_bounds__(256) void k_scatter(const void* eptr, int e, const int* flag,
        const int* rowptr, int* cursor, int* rec, int n) {
    const int nch = 8;
    const int chunk = (n + nch - 1) / nch;
    const bool w64 = (*flag != 0);
    const int stride = gridDim.x * blockDim.x;
    const int tid0 = blockIdx.x * blockDim.x + threadIdx.x;
    for (int ch = 0; ch < nch; ++ch) {
        const int lo = ch * chunk;
        const int hi = min(n, lo + chunk);
        if (w64) {
            const long long* p = (const long long*)eptr;
            for (int i = tid0; i < e; i += stride) {
                int c = (int)p[(long long)e + i];
                if (c >= lo && c < hi) {
                    int s = (int)p[i];
                    int pos = rowptr[c] + atomicAdd(&cursor[c], 1);
                    rec[pos] = s;
                }
            }
        } else {
            const int* p = (const int*)eptr;
            for (int i = tid0; i < e; i += stride) {
                int c = p[(long long)e + i];
                if (c >= lo && c < hi) {
                    int s = p[i];
                    int pos = rowptr[c] + atomicAdd(&cursor[c], 1);
                    rec[pos] = s;
                }
            }
        }
    }
}

// ---------------------------------------------------------------- W1/W2 -> bf16 MFMA-fragment layout
__global__ void k_wprep(const float* __restrict__ W1, const float* __restrict__ W2,
                        unsigned short* __restrict__ W1f, unsigned short* __restrict__ W2f) {
    int t = blockIdx.x * 256 + threadIdx.x;
    if (t < 65536) {
        int e = t & 7, lane = (t >> 3) & 63, nf = (t >> 9) & 7, kt = t >> 12;
        int k = kt * 32 + 8 * (lane >> 4) + e;
        int nn = nf * 16 + (lane & 15);
        W1f[t] = f2bf(W1[k * 128 + nn]);
    } else if (t < 65536 + 8192) {
        int t2 = t - 65536;
        int e = t2 & 7, lane = (t2 >> 3) & 63, nf = (t2 >> 9) & 3, kt2 = t2 >> 11;
        int k = kt2 * 32 + 8 * (lane >> 4) + e;
        int nn = nf * 16 + (lane & 15);
        W2f[t2] = f2bf(W2[k * 64 + nn]);
    }
}

// ---------------------------------------------------------------- MFMA MLP: x0 = relu(x@W1+b1)@W2+b2
// Also emits zs0 = bf16(dinv * x0) for the propagation.
__global__ __launch_bounds__(256) void k_mlp(const float* __restrict__ x,
        const unsigned short* __restrict__ W1f, const float* __restrict__ b1,
        const unsigned short* __restrict__ W2f, const float* __restrict__ b2,
        const float* __restrict__ dinv,
        float* __restrict__ x0, unsigned short* __restrict__ zs0, int n) {
    __shared__ unsigned short Xs[4][64][8];       // A-frags for current K-step (4 KB)
    __shared__ unsigned short Hs[4][4][64][8];    // h in A-frag layout, all K (16 KB)

    const int tid  = threadIdx.x;
    const int lane = tid & 63;
    const int wv   = tid >> 6;
    const int bm0  = blockIdx.x * 64;

    const int sr = tid >> 2;
    const int sk = tid & 3;
    const long long srow = (long long)bm0 + sr;
    const bool svalid = srow < n;
    const float* xp = x + srow * 512 + sk * 8;

    f32x4 acc[4][2];
#pragma unroll
    for (int mf = 0; mf < 4; ++mf)
#pragma unroll
        for (int nf = 0; nf < 2; ++nf) acc[mf][nf] = (f32x4){0.f, 0.f, 0.f, 0.f};

    for (int kt = 0; kt < 16; ++kt) {
        float4 f0 = {0, 0, 0, 0}, f1 = {0, 0, 0, 0};
        if (svalid) {
            f0 = *(const float4*)(xp + kt * 32);
            f1 = *(const float4*)(xp + kt * 32 + 4);
        }
        uint4 pk;
        pk.x = (unsigned int)f2bf(f0.x) | ((unsigned int)f2bf(f0.y) << 16);
        pk.y = (unsigned int)f2bf(f0.z) | ((unsigned int)f2bf(f0.w) << 16);
        pk.z = (unsigned int)f2bf(f1.x) | ((unsigned int)f2bf(f1.y) << 16);
        pk.w = (unsigned int)f2bf(f1.z) | ((unsigned int)f2bf(f1.w) << 16);
        *(uint4*)&Xs[sr >> 4][(sr & 15) + 16 * sk][0] = pk;
        __syncthreads();

        short8 bf[2];
#pragma unroll
        for (int nf = 0; nf < 2; ++nf)
            bf[nf] = *(const short8*)(W1f + (((size_t)kt * 8 + wv * 2 + nf) * 64 + lane) * 8);
#pragma unroll
        for (int mf = 0; mf < 4; ++mf) {
            short8 af = *(const short8*)&Xs[mf][lane][0];
#pragma unroll
            for (int nf = 0; nf < 2; ++nf)
                acc[mf][nf] = __builtin_amdgcn_mfma_f32_16x16x32_bf16(af, bf[nf], acc[mf][nf], 0, 0, 0);
        }
        __syncthreads();
    }

    const int c0 = wv * 32 + (lane & 15);
    const float b1v0 = b1[c0];
    const float b1v1 = b1[c0 + 16];
#pragma unroll
    for (int mf = 0; mf < 4; ++mf) {
#pragma unroll
        for (int nf = 0; nf < 2; ++nf) {
            float bb = nf ? b1v1 : b1v0;
            int k = wv * 32 + nf * 16 + (lane & 15);
#pragma unroll
            for (int r = 0; r < 4; ++r) {
                int row = mf * 16 + 4 * (lane >> 4) + r;
                float h = fmaxf(acc[mf][nf][r] + bb, 0.0f);
                Hs[wv][row >> 4][(row & 15) + 16 * ((k >> 3) & 3)][k & 7] = f2bf(h);
            }
        }
    }
    __syncthreads();

    f32x4 acc2[4];
#pragma unroll
    for (int mf = 0; mf < 4; ++mf) acc2[mf] = (f32x4){0.f, 0.f, 0.f, 0.f};
#pragma unroll
    for (int kt2 = 0; kt2 < 4; ++kt2) {
        short8 bf2 = *(const short8*)(W2f + (((size_t)kt2 * 4 + wv) * 64 + lane) * 8);
#pragma unroll
        for (int mf = 0; mf < 4; ++mf) {
            short8 af2 = *(const short8*)&Hs[kt2][mf][lane][0];
            acc2[mf] = __builtin_amdgcn_mfma_f32_16x16x32_bf16(af2, bf2, acc2[mf], 0, 0, 0);
        }
    }

    const int oc = wv * 16 + (lane & 15);
    const float bo = b2[oc];
#pragma unroll
    for (int mf = 0; mf < 4; ++mf) {
#pragma unroll
        for (int r = 0; r < 4; ++r) {
            long long row = (long long)bm0 + mf * 16 + 4 * (lane >> 4) + r;
            if (row < n) {
                float v = acc2[mf][r] + bo;
                x0[row * 64 + oc] = v;
                zs0[row * 64 + oc] = f2bf(dinv[row] * v);
            }
        }
    }
}

// ---------------------------------------------------------------- propagation
// state zs = bf16(dinv * z); agg[c] = dinv[c] * (sum_src zs[src] + zs[c]).
// One wave per node, lane = channel; 8 independent gather chains.
template<int LAST>
__global__ __launch_bounds__(256) void k_prop(const unsigned short* __restrict__ zs,
        const float* __restrict__ x0, const int* __restrict__ rowptr,
        const int* __restrict__ rec, const float* __restrict__ dinv,
        unsigned short* __restrict__ zsout, float* __restrict__ zfout, int n) {
    int node = __builtin_amdgcn_readfirstlane(blockIdx.x * 4 + (threadIdx.x >> 6));
    if (node >= n) return;
    const int lane = threadIdx.x & 63;
    const long long base = ((long long)node << 6) + lane;
    const int e0 = rowptr[node], e1 = rowptr[node + 1];

    float a0 = bf2f(zs[base]);   // self loop
    float a1 = 0.f, a2 = 0.f, a3 = 0.f, a4 = 0.f, a5 = 0.f, a6 = 0.f, a7 = 0.f;
    int e = e0;
    for (; e + 8 <= e1; e += 8) {
        int s0 = rec[e],     s1 = rec[e + 1], s2 = rec[e + 2], s3 = rec[e + 3];
        int s4 = rec[e + 4], s5 = rec[e + 5], s6 = rec[e + 6], s7 = rec[e + 7];
        float z0 = bf2f(zs[((long long)s0 << 6) + lane]);
        float z1 = bf2f(zs[((long long)s1 << 6) + lane]);
        float z2 = bf2f(zs[((long long)s2 << 6) + lane]);
        float z3 = bf2f(zs[((long long)s3 << 6) + lane]);
        float z4 = bf2f(zs[((long long)s4 << 6) + lane]);
        float z5 = bf2f(zs[((long long)s5 << 6) + lane]);
        float z6 = bf2f(zs[((long long)s6 << 6) + lane]);
        float z7 = bf2f(zs[((long long)s7 << 6) + lane]);
        a0 += z0; a1 += z1; a2 += z2; a3 += z3;
        a4 += z4; a5 += z5; a6 += z6; a7 += z7;
    }
    for (; e < e1; ++e) {
        int s = rec[e];
        a0 += bf2f(zs[((long long)s << 6) + lane]);
    }
    float sum = ((a0 + a1) + (a2 + a3)) + ((a4 + a5) + (a6 + a7));
    float dv = dinv[node];
    float zf = 0.9f * (dv * sum) + 0.1f * x0[base];
    if (LAST) zfout[base] = zf;
    else      zsout[base] = f2bf(dv * zf);
}

// ---------------------------------------------------------------- log_softmax in place (row = wave)
__global__ __launch_bounds__(256) void k_lsm(float* z, int n) {
    int node = blockIdx.x * 4 + (threadIdx.x >> 6);
    if (node >= n) return;
    int lane = threadIdx.x & 63;
    long long base = ((long long)node << 6) + lane;
    float v = z[base];
    float m = v;
#pragma unroll
    for (int o = 32; o >= 1; o >>= 1) m = fmaxf(m, __shfl_xor(m, o, 64));
    float e = expf(v - m);
    float s = e;
#pragma unroll
    for (int o = 32; o >= 1; o >>= 1) s += __shfl_xor(s, o, 64);
    z[base] = v - m - logf(s);
}

// ---------------------------------------------------------------- launch
extern "C" void kernel_launch(void* const* d_in, const int* in_sizes, int n_in,
                              void* d_out, int out_size, void* d_ws, size_t ws_size,
                              hipStream_t stream) {
    const float* x  = (const float*)d_in[0];
    const void*  ei = d_in[1];
    const float* W1 = (const float*)d_in[2];
    const float* b1 = (const float*)d_in[3];
    const float* W2 = (const float*)d_in[4];
    const float* b2 = (const float*)d_in[5];
    float* out = (float*)d_out;

    const int n = in_sizes[0] / 512;
    const int E = in_sizes[1] / 2;

    char* p = (char*)d_ws;
    auto alloc = [&](size_t bytes) {
        void* r = (void*)p;
        p += (bytes + 255) & ~(size_t)255;
        return r;
    };
    int*   cnt    = (int*)alloc((size_t)n * 4);
    int*   cursor = (int*)alloc((size_t)n * 4);
    int*   rowptr = (int*)alloc((size_t)(n + 1) * 4);
    int*   bsum   = (int*)alloc(256 * 4);
    int*   flag   = (int*)alloc(4);
    float* dinv   = (float*)alloc((size_t)n * 4);
    int*   rec    = (int*)alloc((size_t)E * 4);
    float* x0     = (float*)alloc((size_t)n * 64 * 4);
    unsigned short* zsA = (unsigned short*)alloc((size_t)n * 64 * 2);
    unsigned short* zsB = (unsigned short*)alloc((size_t)n * 64 * 2);
    unsigned short* W1f = (unsigned short*)alloc(65536 * 2);
    unsigned short* W2f = (unsigned short*)alloc(8192 * 2);

    const int nb = (n + SCAN_B - 1) / SCAN_B;

    k_init<<<(n + 255) / 256, 256, 0, stream>>>(cnt, cursor, flag, n);
    k_detect<<<2, 256, 0, stream>>>((const int*)ei, E, flag);
    k_wprep<<<(65536 + 8192 + 255) / 256, 256, 0, stream>>>(W1, W2, W1f, W2f);
    k_hist<<<(E + 255) / 256, 256, 0, stream>>>(ei, E, flag, cnt);
    k_dinv<<<(n + 255) / 256, 256, 0, stream>>>(cnt, dinv, n);
    k_scan1<<<nb, SCAN_B, 0, stream>>>(cnt, n, rowptr, bsum);
    k_scan2<<<1, 64, 0, stream>>>(bsum, nb, rowptr, n);
    k_scan3<<<(n + 255) / 256, 256, 0, stream>>>(rowptr, bsum, n);
    k_scatter<<<2048, 256, 0, stream>>>(ei, E, flag, rowptr, cursor, rec, n);
    k_mlp<<<(n + 63) / 64, 256, 0, stream>>>(x, W1f, b1, W2f, b2, dinv, x0, zsA, n);

    const unsigned short* zi = zsA;
    unsigned short* zo = zsB;
    for (int it = 0; it < KITER - 1; ++it) {
        k_prop<0><<<(n + 3) / 4, 256, 0, stream>>>(zi, x0, rowptr, rec, dinv, zo, nullptr, n);
        const unsigned short* t = zi; zi = zo; zo = (unsigned short*)t;
    }
    k_prop<1><<<(n + 3) / 4, 256, 0, stream>>>(zi, x0, rowptr, rec, dinv, nullptr, out, n);
    k_lsm<<<(n + 3) / 4, 256, 0, stream>>>(out, n);
}

// Round 4
// 1416.521 us; speedup vs baseline: 3.7416x; 1.0486x over previous
//
#include <hip/hip_runtime.h>

#define KITER 16
#define NBKT 512   // LDS bucket slots; actual NB = ceil(n/256) = 391 for n=100000

typedef __attribute__((ext_vector_type(8))) short short8;
typedef __attribute__((ext_vector_type(4))) float f32x4;

__device__ __forceinline__ unsigned short f2bf(float f) {
    unsigned int u = __float_as_uint(f);
    u = (u + 0x7fffu + ((u >> 16) & 1u)) >> 16;
    return (unsigned short)u;
}
__device__ __forceinline__ float bf2f(unsigned short h) {
    return __uint_as_float(((unsigned int)h) << 16);
}

// ---------------------------------------------------------------- init
__global__ void k_init(int* cnt, int* flag, int n) {
    int i = blockIdx.x * blockDim.x + threadIdx.x;
    if (i < n) cnt[i] = 0;
    if (blockIdx.x == 0 && threadIdx.x == 0) *flag = 1;
}

// Detect int64 vs int32 edge_index
__global__ void k_detect(const int* ew, int e, int* flag) {
    int t = blockIdx.x * blockDim.x + threadIdx.x;
    if (t < 512 && t < e) {
        if (ew[2 * t + 1] != 0) atomicAnd(flag, 0);
    }
}

// ---------------------------------------------------------------- degree histogram (over col = target)
__global__ void k_hist(const void* eptr, int e, const int* flag, int* cnt) {
    int i = blockIdx.x * blockDim.x + threadIdx.x;
    if (i >= e) return;
    int c;
    if (*flag) c = (int)((const long long*)eptr)[(long long)e + i];
    else       c = ((const int*)eptr)[(long long)e + i];
    atomicAdd(&cnt[c], 1);
}

__global__ void k_dinv(const int* cnt, float* dinv, int n) {
    int i = blockIdx.x * blockDim.x + threadIdx.x;
    if (i >= n) return;
    float d = (float)(cnt[i] + 1);   // +1 self-loop
    dinv[i] = 1.0f / sqrtf(d);
}

// ---------------------------------------------------------------- exclusive scan (row_ptr)
#define SCAN_B 1024
__global__ void k_scan1(const int* cnt, int n, int* rowptr, int* bsum) {
    __shared__ int s[SCAN_B];
    int tid = threadIdx.x;
    int i = blockIdx.x * SCAN_B + tid;
    int v = (i < n) ? cnt[i] : 0;
    s[tid] = v;
    __syncthreads();
    for (int off = 1; off < SCAN_B; off <<= 1) {
        int t = (tid >= off) ? s[tid - off] : 0;
        __syncthreads();
        s[tid] += t;
        __syncthreads();
    }
    if (i < n) rowptr[i] = s[tid] - v;            // exclusive
    if (tid == SCAN_B - 1) bsum[blockIdx.x] = s[tid];
}

__global__ void k_scan2(int* bsum, int nb, int* rowptr, int n) {
    if (blockIdx.x == 0 && threadIdx.x == 0) {
        int run = 0;
        for (int b = 0; b < nb; ++b) { int t = bsum[b]; bsum[b] = run; run += t; }
        rowptr[n] = run;
    }
}

__global__ void k_scan3(int* rowptr, const int* bsum, int n) {
    int i = blockIdx.x * blockDim.x + threadIdx.x;
    if (i < n) rowptr[i] += bsum[i / SCAN_B];
}

__global__ void k_binit(const int* rowptr, int* bcur, int n) {
    int b = blockIdx.x * blockDim.x + threadIdx.x;
    int NB = (n + 255) >> 8;
    if (b < NB) bcur[b] = rowptr[min(n, b << 8)];
}

// ---------------------------------------------------------------- phase A: bucket partition
// Bucket = 256 consecutive target nodes. Per-WG LDS histogram over its edge
// stripe, one global atomicAdd per (WG,bucket) reserves a contiguous run ->
// ebuf writes are ~full-line sequential runs (391 cursor streams only).
__global__ __launch_bounds__(256) void k_bucketA(const void* eptr, int E, const int* flag,
        int* bcur, long long* ebuf, int n) {
    __shared__ int hist[NBKT];
    __shared__ int lbase[NBKT];
    __shared__ int lcur[NBKT];
    const int NB = (n + 255) >> 8;
    const int wg = blockIdx.x, nwg = gridDim.x, tid = threadIdx.x;
    const int s0 = (int)(((long long)E * wg) / nwg);
    const int s1 = (int)(((long long)E * (wg + 1)) / nwg);
    for (int b = tid; b < NB; b += 256) { hist[b] = 0; lcur[b] = 0; }
    __syncthreads();
    const bool w64 = (*flag != 0);
    if (w64) {
        const long long* pc = (const long long*)eptr + E;
        for (int i = s0 + tid; i < s1; i += 256)
            atomicAdd(&hist[((int)pc[i]) >> 8], 1);
    } else {
        const int* pc = (const int*)eptr + E;
        for (int i = s0 + tid; i < s1; i += 256)
            atomicAdd(&hist[pc[i] >> 8], 1);
    }
    __syncthreads();
    for (int b = tid; b < NB; b += 256)
        lbase[b] = hist[b] ? atomicAdd(&bcur[b], hist[b]) : 0;
    __syncthreads();
    if (w64) {
        const long long* ps = (const long long*)eptr;
        const long long* pc = ps + E;
        for (int i = s0 + tid; i < s1; i += 256) {
            int c = (int)pc[i];
            int s = (int)ps[i];
            int b = c >> 8;
            int pos = lbase[b] + atomicAdd(&lcur[b], 1);
            ebuf[pos] = ((long long)c << 32) | (unsigned int)s;
        }
    } else {
        const int* ps = (const int*)eptr;
        const int* pc = ps + E;
        for (int i = s0 + tid; i < s1; i += 256) {
            int c = pc[i];
            int s = ps[i];
            int b = c >> 8;
            int pos = lbase[b] + atomicAdd(&lcur[b], 1);
            ebuf[pos] = ((long long)c << 32) | (unsigned int)s;
        }
    }
}

// ---------------------------------------------------------------- phase B: within-bucket CSR scatter
// One WG per bucket; rec window ~32 KB (single CU, L2-local, full lines).
__global__ __launch_bounds__(256) void k_bucketB(const long long* ebuf, const int* rowptr,
        int* rec, int n) {
    __shared__ int cur[256];
    const int lo = blockIdx.x << 8;
    const int hi = min(n, lo + 256);
    cur[threadIdx.x] = 0;
    __syncthreads();
    const int e0 = rowptr[lo], e1 = rowptr[hi];
    for (int i = e0 + threadIdx.x; i < e1; i += 256) {
        long long q = ebuf[i];
        int c = (int)(q >> 32);
        int s = (int)q;
        int pos = rowptr[c] + atomicAdd(&cur[c - lo], 1);
        rec[pos] = s;
    }
}

// ---------------------------------------------------------------- W1/W2 -> bf16 MFMA-fragment layout
__global__ void k_wprep(const float* __restrict__ W1, const float* __restrict__ W2,
                        unsigned short* __restrict__ W1f, unsigned short* __restrict__ W2f) {
    int t = blockIdx.x * 256 + threadIdx.x;
    if (t < 65536) {
        int e = t & 7, lane = (t >> 3) & 63, nf = (t >> 9) & 7, kt = t >> 12;
        int k = kt * 32 + 8 * (lane >> 4) + e;
        int nn = nf * 16 + (lane & 15);
        W1f[t] = f2bf(W1[k * 128 + nn]);
    } else if (t < 65536 + 8192) {
        int t2 = t - 65536;
        int e = t2 & 7, lane = (t2 >> 3) & 63, nf = (t2 >> 9) & 3, kt2 = t2 >> 11;
        int k = kt2 * 32 + 8 * (lane >> 4) + e;
        int nn = nf * 16 + (lane & 15);
        W2f[t2] = f2bf(W2[k * 64 + nn]);
    }
}

// ---------------------------------------------------------------- MFMA MLP: v = relu(x@W1+b1)@W2+b2
// Emits ax0 = bf16(0.1*v) and zs0 = bf16(dinv*v). No fp32 x0 materialized.
__global__ __launch_bounds__(256) void k_mlp(const float* __restrict__ x,
        const unsigned short* __restrict__ W1f, const float* __restrict__ b1,
        const unsigned short* __restrict__ W2f, const float* __restrict__ b2,
        const float* __restrict__ dinv,
        unsigned short* __restrict__ ax0, unsigned short* __restrict__ zs0, int n) {
    __shared__ unsigned short Xs[4][64][8];       // A-frags for current K-step (4 KB)
    __shared__ unsigned short Hs[4][4][64][8];    // h in A-frag layout, all K (16 KB)

    const int tid  = threadIdx.x;
    const int lane = tid & 63;
    const int wv   = tid >> 6;
    const int bm0  = blockIdx.x * 64;

    const int sr = tid >> 2;
    const int sk = tid & 3;
    const long long srow = (long long)bm0 + sr;
    const bool svalid = srow < n;
    const float* xp = x + srow * 512 + sk * 8;

    f32x4 acc[4][2];
#pragma unroll
    for (int mf = 0; mf < 4; ++mf)
#pragma unroll
        for (int nf = 0; nf < 2; ++nf) acc[mf][nf] = (f32x4){0.f, 0.f, 0.f, 0.f};

    for (int kt = 0; kt < 16; ++kt) {
        float4 f0 = {0, 0, 0, 0}, f1 = {0, 0, 0, 0};
        if (svalid) {
            f0 = *(const float4*)(xp + kt * 32);
            f1 = *(const float4*)(xp + kt * 32 + 4);
        }
        uint4 pk;
        pk.x = (unsigned int)f2bf(f0.x) | ((unsigned int)f2bf(f0.y) << 16);
        pk.y = (unsigned int)f2bf(f0.z) | ((unsigned int)f2bf(f0.w) << 16);
        pk.z = (unsigned int)f2bf(f1.x) | ((unsigned int)f2bf(f1.y) << 16);
        pk.w = (unsigned int)f2bf(f1.z) | ((unsigned int)f2bf(f1.w) << 16);
        *(uint4*)&Xs[sr >> 4][(sr & 15) + 16 * sk][0] = pk;
        __syncthreads();

        short8 bf[2];
#pragma unroll
        for (int nf = 0; nf < 2; ++nf)
            bf[nf] = *(const short8*)(W1f + (((size_t)kt * 8 + wv * 2 + nf) * 64 + lane) * 8);
#pragma unroll
        for (int mf = 0; mf < 4; ++mf) {
            short8 af = *(const short8*)&Xs[mf][lane][0];
#pragma unroll
            for (int nf = 0; nf < 2; ++nf)
                acc[mf][nf] = __builtin_amdgcn_mfma_f32_16x16x32_bf16(af, bf[nf], acc[mf][nf], 0, 0, 0);
        }
        __syncthreads();
    }

    const int c0 = wv * 32 + (lane & 15);
    const float b1v0 = b1[c0];
    const float b1v1 = b1[c0 + 16];
#pragma unroll
    for (int mf = 0; mf < 4; ++mf) {
#pragma unroll
        for (int nf = 0; nf < 2; ++nf) {
            float bb = nf ? b1v1 : b1v0;
            int k = wv * 32 + nf * 16 + (lane & 15);
#pragma unroll
            for (int r = 0; r < 4; ++r) {
                int row = mf * 16 + 4 * (lane >> 4) + r;
                float h = fmaxf(acc[mf][nf][r] + bb, 0.0f);
                Hs[wv][row >> 4][(row & 15) + 16 * ((k >> 3) & 3)][k & 7] = f2bf(h);
            }
        }
    }
    __syncthreads();

    f32x4 acc2[4];
#pragma unroll
    for (int mf = 0; mf < 4; ++mf) acc2[mf] = (f32x4){0.f, 0.f, 0.f, 0.f};
#pragma unroll
    for (int kt2 = 0; kt2 < 4; ++kt2) {
        short8 bf2 = *(const short8*)(W2f + (((size_t)kt2 * 4 + wv) * 64 + lane) * 8);
#pragma unroll
        for (int mf = 0; mf < 4; ++mf) {
            short8 af2 = *(const short8*)&Hs[kt2][mf][lane][0];
            acc2[mf] = __builtin_amdgcn_mfma_f32_16x16x32_bf16(af2, bf2, acc2[mf], 0, 0, 0);
        }
    }

    const int oc = wv * 16 + (lane & 15);
    const float bo = b2[oc];
#pragma unroll
    for (int mf = 0; mf < 4; ++mf) {
#pragma unroll
        for (int r = 0; r < 4; ++r) {
            long long row = (long long)bm0 + mf * 16 + 4 * (lane >> 4) + r;
            if (row < n) {
                float v = acc2[mf][r] + bo;
                ax0[row * 64 + oc] = f2bf(0.1f * v);
                zs0[row * 64 + oc] = f2bf(dinv[row] * v);
            }
        }
    }
}

// ---------------------------------------------------------------- propagation
// state zs = bf16(dinv * z); z_new[c] = 0.9*dinv[c]*(sum_src zs[src] + zs[c]) + 0.1*x0[c]
__global__ __launch_bounds__(256) void k_lsm(float* z, int n);

template<int LAST>
__global__ __launch_bounds__(256) void k_prop(const unsigned short* __restrict__ zs,
        const unsigned short* __restrict__ ax0, const int* __restrict__ rowptr,
        const int* __restrict__ rec, const float* __restrict__ dinv,
        unsigned short* __restrict__ zsout, float* __restrict__ zfout, int n) {
    int node = __builtin_amdgcn_readfirstlane(blockIdx.x * 4 + (threadIdx.x >> 6));
    if (node >= n) return;
    const int lane = threadIdx.x & 63;
    const long long base = ((long long)node << 6) + lane;
    const int e0 = rowptr[node], e1 = rowptr[node + 1];

    float a0 = bf2f(zs[base]);   // self loop
    float a1 = 0.f, a2 = 0.f, a3 = 0.f, a4 = 0.f, a5 = 0.f, a6 = 0.f, a7 = 0.f;
    int e = e0;
    for (; e + 8 <= e1; e += 8) {
        int s0 = rec[e],     s1 = rec[e + 1], s2 = rec[e + 2], s3 = rec[e + 3];
        int s4 = rec[e + 4], s5 = rec[e + 5], s6 = rec[e + 6], s7 = rec[e + 7];
        float z0 = bf2f(zs[((long long)s0 << 6) + lane]);
        float z1 = bf2f(zs[((long long)s1 << 6) + lane]);
        float z2 = bf2f(zs[((long long)s2 << 6) + lane]);
        float z3 = bf2f(zs[((long long)s3 << 6) + lane]);
        float z4 = bf2f(zs[((long long)s4 << 6) + lane]);
        float z5 = bf2f(zs[((long long)s5 << 6) + lane]);
        float z6 = bf2f(zs[((long long)s6 << 6) + lane]);
        float z7 = bf2f(zs[((long long)s7 << 6) + lane]);
        a0 += z0; a1 += z1; a2 += z2; a3 += z3;
        a4 += z4; a5 += z5; a6 += z6; a7 += z7;
    }
    for (; e < e1; ++e) {
        int s = rec[e];
        a0 += bf2f(zs[((long long)s << 6) + lane]);
    }
    float sum = ((a0 + a1) + (a2 + a3)) + ((a4 + a5) + (a6 + a7));
    float dv = dinv[node];
    float zf = 0.9f * (dv * sum) + bf2f(ax0[base]);
    if (LAST) zfout[base] = zf;
    else      zsout[base] = f2bf(dv * zf);
}

// ---------------------------------------------------------------- log_softmax in place (row = wave)
__global__ __launch_bounds__(256) void k_lsm(float* z, int n) {
    int node = blockIdx.x * 4 + (threadIdx.x >> 6);
    if (node >= n) return;
    int lane = threadIdx.x & 63;
    long long base = ((long long)node << 6) + lane;
    float v = z[base];
    float m = v;
#pragma unroll
    for (int o = 32; o >= 1; o >>= 1) m = fmaxf(m, __shfl_xor(m, o, 64));
    float e = expf(v - m);
    float s = e;
#pragma unroll
    for (int o = 32; o >= 1; o >>= 1) s += __shfl_xor(s, o, 64);
    z[base] = v - m - logf(s);
}

// ---------------------------------------------------------------- launch
extern "C" void kernel_launch(void* const* d_in, const int* in_sizes, int n_in,
                              void* d_out, int out_size, void* d_ws, size_t ws_size,
                              hipStream_t stream) {
    const float* x  = (const float*)d_in[0];
    const void*  ei = d_in[1];
    const float* W1 = (const float*)d_in[2];
    const float* b1 = (const float*)d_in[3];
    const float* W2 = (const float*)d_in[4];
    const float* b2 = (const float*)d_in[5];
    float* out = (float*)d_out;

    const int n = in_sizes[0] / 512;
    const int E = in_sizes[1] / 2;
    const int NB = (n + 255) >> 8;

    char* p = (char*)d_ws;
    auto alloc = [&](size_t bytes) {
        void* r = (void*)p;
        p += (bytes + 255) & ~(size_t)255;
        return r;
    };
    int*   cnt    = (int*)alloc((size_t)n * 4);
    int*   rowptr = (int*)alloc((size_t)(n + 1) * 4);
    int*   bsum   = (int*)alloc(256 * 4);
    int*   flag   = (int*)alloc(4);
    int*   bcur   = (int*)alloc(NBKT * 4);
    float* dinv   = (float*)alloc((size_t)n * 4);
    int*   rec    = (int*)alloc((size_t)E * 4);
    long long* ebuf = (long long*)alloc((size_t)E * 8);
    unsigned short* ax0 = (unsigned short*)alloc((size_t)n * 64 * 2);
    unsigned short* zsA = (unsigned short*)alloc((size_t)n * 64 * 2);
    unsigned short* zsB = (unsigned short*)alloc((size_t)n * 64 * 2);
    unsigned short* W1f = (unsigned short*)alloc(65536 * 2);
    unsigned short* W2f = (unsigned short*)alloc(8192 * 2);

    const int nb = (n + SCAN_B - 1) / SCAN_B;

    k_init<<<(n + 255) / 256, 256, 0, stream>>>(cnt, flag, n);
    k_detect<<<2, 256, 0, stream>>>((const int*)ei, E, flag);
    k_wprep<<<(65536 + 8192 + 255) / 256, 256, 0, stream>>>(W1, W2, W1f, W2f);
    k_hist<<<(E + 255) / 256, 256, 0, stream>>>(ei, E, flag, cnt);
    k_dinv<<<(n + 255) / 256, 256, 0, stream>>>(cnt, dinv, n);
    k_scan1<<<nb, SCAN_B, 0, stream>>>(cnt, n, rowptr, bsum);
    k_scan2<<<1, 64, 0, stream>>>(bsum, nb, rowptr, n);
    k_scan3<<<(n + 255) / 256, 256, 0, stream>>>(rowptr, bsum, n);
    k_binit<<<(NBKT + 255) / 256, 256, 0, stream>>>(rowptr, bcur, n);
    k_bucketA<<<512, 256, 0, stream>>>(ei, E, flag, bcur, ebuf, n);
    k_bucketB<<<NB, 256, 0, stream>>>(ebuf, rowptr, rec, n);
    k_mlp<<<(n + 63) / 64, 256, 0, stream>>>(x, W1f, b1, W2f, b2, dinv, ax0, zsA, n);

    const unsigned short* zi = zsA;
    unsigned short* zo = zsB;
    for (int it = 0; it < KITER - 1; ++it) {
        k_prop<0><<<(n + 3) / 4, 256, 0, stream>>>(zi, ax0, rowptr, rec, dinv, zo, nullptr, n);
        const unsigned short* t = zi; zi = zo; zo = (unsigned short*)t;
    }
    k_prop<1><<<(n + 3) / 4, 256, 0, stream>>>(zi, ax0, rowptr, rec, dinv, nullptr, out, n);
    k_lsm<<<(n + 3) / 4, 256, 0, stream>>>(out, n);
}

// Round 5
// 1266.786 us; speedup vs baseline: 4.1839x; 1.1182x over previous
//
#include <hip/hip_runtime.h>

#define KITER 16
#define NBKT 512   // max buckets (bucket = 256 target nodes); n <= 131072

typedef __attribute__((ext_vector_type(8))) short short8;
typedef __attribute__((ext_vector_type(4))) float f32x4;

__device__ __forceinline__ unsigned short f2bf(float f) {
    unsigned int u = __float_as_uint(f);
    u = (u + 0x7fffu + ((u >> 16) & 1u)) >> 16;
    return (unsigned short)u;
}
__device__ __forceinline__ float bf2f(unsigned short h) {
    return __uint_as_float(((unsigned int)h) << 16);
}

// ---------------------------------------------------------------- init
__global__ void k_init(int* bktcnt, int* flag) {
    int i = blockIdx.x * blockDim.x + threadIdx.x;
    if (i < NBKT) bktcnt[i] = 0;
    if (i == 0) *flag = 1;
}

// Detect int64 vs int32 edge_index
__global__ void k_detect(const int* ew, int e, int* flag) {
    int t = blockIdx.x * blockDim.x + threadIdx.x;
    if (t < 512 && t < e) {
        if (ew[2 * t + 1] != 0) atomicAnd(flag, 0);
    }
}

// ---------------------------------------------------------------- bucket histogram (391 buckets, LDS-staged)
__global__ __launch_bounds__(256) void k_bhist(const void* eptr, int E, const int* flag,
        int* bktcnt, int n) {
    __shared__ int h[NBKT];
    const int NB = (n + 255) >> 8;
    for (int i = threadIdx.x; i < NB; i += 256) h[i] = 0;
    __syncthreads();
    const int tid0 = blockIdx.x * 256 + threadIdx.x;
    const int stride = gridDim.x * 256;
    if (*flag) {
        const long long* pc = (const long long*)eptr + E;
        for (int i = tid0; i < E; i += stride) atomicAdd(&h[((int)pc[i]) >> 8], 1);
    } else {
        const int* pc = (const int*)eptr + E;
        for (int i = tid0; i < E; i += stride) atomicAdd(&h[pc[i] >> 8], 1);
    }
    __syncthreads();
    for (int i = threadIdx.x; i < NB; i += 256) if (h[i]) atomicAdd(&bktcnt[i], h[i]);
}

// ---------------------------------------------------------------- scan bucket totals -> bases
__global__ __launch_bounds__(512) void k_bscan(const int* bktcnt, int* bktbase, int* bcur, int n) {
    __shared__ int s[NBKT];
    const int NB = (n + 255) >> 8;
    const int tid = threadIdx.x;
    int v = (tid < NB) ? bktcnt[tid] : 0;
    s[tid] = v;
    __syncthreads();
    for (int off = 1; off < NBKT; off <<= 1) {
        int t = (tid >= off) ? s[tid - off] : 0;
        __syncthreads();
        s[tid] += t;
        __syncthreads();
    }
    int excl = s[tid] - v;
    if (tid < NB) { bktbase[tid] = excl; bcur[tid] = excl; }
    if (tid == NB - 1) bktbase[NB] = s[tid];
}

// ---------------------------------------------------------------- phase A: bucket partition
// ebuf entry: (src << 8) | (c & 255)  -- requires n < 2^24
__global__ __launch_bounds__(256) void k_bucketA(const void* eptr, int E, const int* flag,
        int* bcur, unsigned int* ebuf, int n) {
    __shared__ int hist[NBKT];
    __shared__ int lbase[NBKT];
    __shared__ int lcur[NBKT];
    const int NB = (n + 255) >> 8;
    const int wg = blockIdx.x, nwg = gridDim.x, tid = threadIdx.x;
    const int s0 = (int)(((long long)E * wg) / nwg);
    const int s1 = (int)(((long long)E * (wg + 1)) / nwg);
    for (int b = tid; b < NB; b += 256) { hist[b] = 0; lcur[b] = 0; }
    __syncthreads();
    const bool w64 = (*flag != 0);
    if (w64) {
        const long long* pc = (const long long*)eptr + E;
        for (int i = s0 + tid; i < s1; i += 256)
            atomicAdd(&hist[((int)pc[i]) >> 8], 1);
    } else {
        const int* pc = (const int*)eptr + E;
        for (int i = s0 + tid; i < s1; i += 256)
            atomicAdd(&hist[pc[i] >> 8], 1);
    }
    __syncthreads();
    for (int b = tid; b < NB; b += 256)
        lbase[b] = hist[b] ? atomicAdd(&bcur[b], hist[b]) : 0;
    __syncthreads();
    if (w64) {
        const long long* ps = (const long long*)eptr;
        const long long* pc = ps + E;
        for (int i = s0 + tid; i < s1; i += 256) {
            int c = (int)pc[i];
            int s = (int)ps[i];
            int b = c >> 8;
            int pos = lbase[b] + atomicAdd(&lcur[b], 1);
            ebuf[pos] = ((unsigned int)s << 8) | (unsigned int)(c & 255);
        }
    } else {
        const int* ps = (const int*)eptr;
        const int* pc = ps + E;
        for (int i = s0 + tid; i < s1; i += 256) {
            int c = pc[i];
            int s = ps[i];
            int b = c >> 8;
            int pos = lbase[b] + atomicAdd(&lcur[b], 1);
            ebuf[pos] = ((unsigned int)s << 8) | (unsigned int)(c & 255);
        }
    }
}

// ---------------------------------------------------------------- phase B: within-bucket CSR + rowptr + dinv
__global__ __launch_bounds__(256) void k_bucketB(const unsigned int* ebuf, const int* bktbase,
        int* rowptr, int* rec, float* dinv, int n) {
    __shared__ int cnt[256];
    __shared__ int base[256];
    __shared__ int cur[256];
    const int NB = (n + 255) >> 8;
    const int b = blockIdx.x;
    const int lo = b << 8;
    const int nloc = min(256, n - lo);
    const int tid = threadIdx.x;
    cnt[tid] = 0; cur[tid] = 0;
    __syncthreads();
    const int e0 = bktbase[b], e1 = bktbase[b + 1];
    for (int i = e0 + tid; i < e1; i += 256)
        atomicAdd(&cnt[ebuf[i] & 255u], 1);
    __syncthreads();
    int v = cnt[tid];
    base[tid] = v;
    __syncthreads();
    for (int off = 1; off < 256; off <<= 1) {
        int t = (tid >= off) ? base[tid - off] : 0;
        __syncthreads();
        base[tid] += t;
        __syncthreads();
    }
    int ebase = e0 + base[tid] - v;       // exclusive within window + window base
    if (tid < nloc) {
        rowptr[lo + tid] = ebase;
        dinv[lo + tid] = 1.0f / sqrtf((float)(v + 1));
    }
    base[tid] = ebase;
    __syncthreads();
    if (b == 0 && tid == 0) rowptr[n] = bktbase[NB];
    for (int i = e0 + tid; i < e1; i += 256) {
        unsigned int q = ebuf[i];
        int cl = (int)(q & 255u);
        int pos = base[cl] + atomicAdd(&cur[cl], 1);
        rec[pos] = (int)(q >> 8);
    }
}

// ---------------------------------------------------------------- W1/W2 -> bf16 MFMA-fragment layout
__global__ void k_wprep(const float* __restrict__ W1, const float* __restrict__ W2,
                        unsigned short* __restrict__ W1f, unsigned short* __restrict__ W2f) {
    int t = blockIdx.x * 256 + threadIdx.x;
    if (t < 65536) {
        int e = t & 7, lane = (t >> 3) & 63, nf = (t >> 9) & 7, kt = t >> 12;
        int k = kt * 32 + 8 * (lane >> 4) + e;
        int nn = nf * 16 + (lane & 15);
        W1f[t] = f2bf(W1[k * 128 + nn]);
    } else if (t < 65536 + 8192) {
        int t2 = t - 65536;
        int e = t2 & 7, lane = (t2 >> 3) & 63, nf = (t2 >> 9) & 3, kt2 = t2 >> 11;
        int k = kt2 * 32 + 8 * (lane >> 4) + e;
        int nn = nf * 16 + (lane & 15);
        W2f[t2] = f2bf(W2[k * 64 + nn]);
    }
}

// ---------------------------------------------------------------- MFMA MLP: v = relu(x@W1+b1)@W2+b2
// Emits ax0 = bf16(0.1*v) and zs0 = bf16(dinv*v).
__global__ __launch_bounds__(256) void k_mlp(const float* __restrict__ x,
        const unsigned short* __restrict__ W1f, const float* __restrict__ b1,
        const unsigned short* __restrict__ W2f, const float* __restrict__ b2,
        const float* __restrict__ dinv,
        unsigned short* __restrict__ ax0, unsigned short* __restrict__ zs0, int n) {
    __shared__ unsigned short Xs[4][64][8];
    __shared__ unsigned short Hs[4][4][64][8];

    const int tid  = threadIdx.x;
    const int lane = tid & 63;
    const int wv   = tid >> 6;
    const int bm0  = blockIdx.x * 64;

    const int sr = tid >> 2;
    const int sk = tid & 3;
    const long long srow = (long long)bm0 + sr;
    const bool svalid = srow < n;
    const float* xp = x + srow * 512 + sk * 8;

    f32x4 acc[4][2];
#pragma unroll
    for (int mf = 0; mf < 4; ++mf)
#pragma unroll
        for (int nf = 0; nf < 2; ++nf) acc[mf][nf] = (f32x4){0.f, 0.f, 0.f, 0.f};

    for (int kt = 0; kt < 16; ++kt) {
        float4 f0 = {0, 0, 0, 0}, f1 = {0, 0, 0, 0};
        if (svalid) {
            f0 = *(const float4*)(xp + kt * 32);
            f1 = *(const float4*)(xp + kt * 32 + 4);
        }
        uint4 pk;
        pk.x = (unsigned int)f2bf(f0.x) | ((unsigned int)f2bf(f0.y) << 16);
        pk.y = (unsigned int)f2bf(f0.z) | ((unsigned int)f2bf(f0.w) << 16);
        pk.z = (unsigned int)f2bf(f1.x) | ((unsigned int)f2bf(f1.y) << 16);
        pk.w = (unsigned int)f2bf(f1.z) | ((unsigned int)f2bf(f1.w) << 16);
        *(uint4*)&Xs[sr >> 4][(sr & 15) + 16 * sk][0] = pk;
        __syncthreads();

        short8 bf[2];
#pragma unroll
        for (int nf = 0; nf < 2; ++nf)
            bf[nf] = *(const short8*)(W1f + (((size_t)kt * 8 + wv * 2 + nf) * 64 + lane) * 8);
#pragma unroll
        for (int mf = 0; mf < 4; ++mf) {
            short8 af = *(const short8*)&Xs[mf][lane][0];
#pragma unroll
            for (int nf = 0; nf < 2; ++nf)
                acc[mf][nf] = __builtin_amdgcn_mfma_f32_16x16x32_bf16(af, bf[nf], acc[mf][nf], 0, 0, 0);
        }
        __syncthreads();
    }

    const int c0 = wv * 32 + (lane & 15);
    const float b1v0 = b1[c0];
    const float b1v1 = b1[c0 + 16];
#pragma unroll
    for (int mf = 0; mf < 4; ++mf) {
#pragma unroll
        for (int nf = 0; nf < 2; ++nf) {
            float bb = nf ? b1v1 : b1v0;
            int k = wv * 32 + nf * 16 + (lane & 15);
#pragma unroll
            for (int r = 0; r < 4; ++r) {
                int row = mf * 16 + 4 * (lane >> 4) + r;
                float h = fmaxf(acc[mf][nf][r] + bb, 0.0f);
                Hs[wv][row >> 4][(row & 15) + 16 * ((k >> 3) & 3)][k & 7] = f2bf(h);
            }
        }
    }
    __syncthreads();

    f32x4 acc2[4];
#pragma unroll
    for (int mf = 0; mf < 4; ++mf) acc2[mf] = (f32x4){0.f, 0.f, 0.f, 0.f};
#pragma unroll
    for (int kt2 = 0; kt2 < 4; ++kt2) {
        short8 bf2 = *(const short8*)(W2f + (((size_t)kt2 * 4 + wv) * 64 + lane) * 8);
#pragma unroll
        for (int mf = 0; mf < 4; ++mf) {
            short8 af2 = *(const short8*)&Hs[kt2][mf][lane][0];
            acc2[mf] = __builtin_amdgcn_mfma_f32_16x16x32_bf16(af2, bf2, acc2[mf], 0, 0, 0);
        }
    }

    const int oc = wv * 16 + (lane & 15);
    const float bo = b2[oc];
#pragma unroll
    for (int mf = 0; mf < 4; ++mf) {
#pragma unroll
        for (int r = 0; r < 4; ++r) {
            long long row = (long long)bm0 + mf * 16 + 4 * (lane >> 4) + r;
            if (row < n) {
                float v = acc2[mf][r] + bo;
                ax0[row * 64 + oc] = f2bf(0.1f * v);
                zs0[row * 64 + oc] = f2bf(dinv[row] * v);
            }
        }
    }
}

// ---------------------------------------------------------------- propagation
// LAST=1 fuses log_softmax and writes fp32 out.
template<int LAST>
__global__ __launch_bounds__(256) void k_prop(const unsigned short* __restrict__ zs,
        const unsigned short* __restrict__ ax0, const int* __restrict__ rowptr,
        const int* __restrict__ rec, const float* __restrict__ dinv,
        unsigned short* __restrict__ zsout, float* __restrict__ zfout, int n) {
    int node = __builtin_amdgcn_readfirstlane(blockIdx.x * 4 + (threadIdx.x >> 6));
    if (node >= n) return;
    const int lane = threadIdx.x & 63;
    const long long base = ((long long)node << 6) + lane;
    const int e0 = rowptr[node], e1 = rowptr[node + 1];

    float a0 = bf2f(zs[base]);   // self loop
    float a1 = 0.f, a2 = 0.f, a3 = 0.f, a4 = 0.f, a5 = 0.f, a6 = 0.f, a7 = 0.f;
    int e = e0;
    for (; e + 8 <= e1; e += 8) {
        int s0 = rec[e],     s1 = rec[e + 1], s2 = rec[e + 2], s3 = rec[e + 3];
        int s4 = rec[e + 4], s5 = rec[e + 5], s6 = rec[e + 6], s7 = rec[e + 7];
        float z0 = bf2f(zs[((long long)s0 << 6) + lane]);
        float z1 = bf2f(zs[((long long)s1 << 6) + lane]);
        float z2 = bf2f(zs[((long long)s2 << 6) + lane]);
        float z3 = bf2f(zs[((long long)s3 << 6) + lane]);
        float z4 = bf2f(zs[((long long)s4 << 6) + lane]);
        float z5 = bf2f(zs[((long long)s5 << 6) + lane]);
        float z6 = bf2f(zs[((long long)s6 << 6) + lane]);
        float z7 = bf2f(zs[((long long)s7 << 6) + lane]);
        a0 += z0; a1 += z1; a2 += z2; a3 += z3;
        a4 += z4; a5 += z5; a6 += z6; a7 += z7;
    }
    for (; e < e1; ++e) {
        int s = rec[e];
        a0 += bf2f(zs[((long long)s << 6) + lane]);
    }
    float sum = ((a0 + a1) + (a2 + a3)) + ((a4 + a5) + (a6 + a7));
    float dv = dinv[node];
    float zf = 0.9f * (dv * sum) + bf2f(ax0[base]);
    if (LAST) {
        float m = zf;
#pragma unroll
        for (int o = 32; o >= 1; o >>= 1) m = fmaxf(m, __shfl_xor(m, o, 64));
        float ev = expf(zf - m);
        float s = ev;
#pragma unroll
        for (int o = 32; o >= 1; o >>= 1) s += __shfl_xor(s, o, 64);
        zfout[base] = zf - m - logf(s);
    } else {
        zsout[base] = f2bf(dv * zf);
    }
}

// ---------------------------------------------------------------- launch
extern "C" void kernel_launch(void* const* d_in, const int* in_sizes, int n_in,
                              void* d_out, int out_size, void* d_ws, size_t ws_size,
                              hipStream_t stream) {
    const float* x  = (const float*)d_in[0];
    const void*  ei = d_in[1];
    const float* W1 = (const float*)d_in[2];
    const float* b1 = (const float*)d_in[3];
    const float* W2 = (const float*)d_in[4];
    const float* b2 = (const float*)d_in[5];
    float* out = (float*)d_out;

    const int n = in_sizes[0] / 512;
    const int E = in_sizes[1] / 2;
    const int NB = (n + 255) >> 8;

    char* p = (char*)d_ws;
    auto alloc = [&](size_t bytes) {
        void* r = (void*)p;
        p += (bytes + 255) & ~(size_t)255;
        return r;
    };
    int*   rowptr  = (int*)alloc((size_t)(n + 1) * 4);
    int*   flag    = (int*)alloc(4);
    int*   bktcnt  = (int*)alloc(NBKT * 4);
    int*   bktbase = (int*)alloc((NBKT + 1) * 4);
    int*   bcur    = (int*)alloc(NBKT * 4);
    float* dinv    = (float*)alloc((size_t)n * 4);
    int*   rec     = (int*)alloc((size_t)E * 4);
    unsigned int* ebuf = (unsigned int*)alloc((size_t)E * 4);
    unsigned short* ax0 = (unsigned short*)alloc((size_t)n * 64 * 2);
    unsigned short* zsA = (unsigned short*)alloc((size_t)n * 64 * 2);
    unsigned short* zsB = (unsigned short*)alloc((size_t)n * 64 * 2);
    unsigned short* W1f = (unsigned short*)alloc(65536 * 2);
    unsigned short* W2f = (unsigned short*)alloc(8192 * 2);

    k_init<<<2, 256, 0, stream>>>(bktcnt, flag);
    k_detect<<<2, 256, 0, stream>>>((const int*)ei, E, flag);
    k_wprep<<<(65536 + 8192 + 255) / 256, 256, 0, stream>>>(W1, W2, W1f, W2f);
    k_bhist<<<512, 256, 0, stream>>>(ei, E, flag, bktcnt, n);
    k_bscan<<<1, 512, 0, stream>>>(bktcnt, bktbase, bcur, n);
    k_bucketA<<<512, 256, 0, stream>>>(ei, E, flag, bcur, ebuf, n);
    k_bucketB<<<NB, 256, 0, stream>>>(ebuf, bktbase, rowptr, rec, dinv, n);
    k_mlp<<<(n + 63) / 64, 256, 0, stream>>>(x, W1f, b1, W2f, b2, dinv, ax0, zsA, n);

    const unsigned short* zi = zsA;
    unsigned short* zo = zsB;
    for (int it = 0; it < KITER - 1; ++it) {
        k_prop<0><<<(n + 3) / 4, 256, 0, stream>>>(zi, ax0, rowptr, rec, dinv, zo, nullptr, n);
        const unsigned short* t = zi; zi = zo; zo = (unsigned short*)t;
    }
    k_prop<1><<<(n + 3) / 4, 256, 0, stream>>>(zi, ax0, rowptr, rec, dinv, nullptr, out, n);
}